// Round 4
// baseline (29971.750 us; speedup 1.0000x reference)
//
#include <hip/hip_runtime.h>

typedef unsigned short u16;
typedef unsigned int u32;
typedef short v8s __attribute__((ext_vector_type(8)));
typedef float v4f __attribute__((ext_vector_type(4)));

#define DEV static __device__ __forceinline__

DEV float bf2f(u16 u) { union { u32 i; float f; } v; v.i = ((u32)u) << 16; return v.f; }
DEV u16 f2bf(float f) {
  union { float f; u32 i; } v; v.f = f;
  u32 i = v.i + 0x7FFFu + ((v.i >> 16) & 1u);
  return (u16)(i >> 16);
}
DEV float sigm(float x) { return 1.0f / (1.0f + __expf(-x)); }
DEV v4f mfma16(v8s a, v8s b, v4f c) {
  return __builtin_amdgcn_mfma_f32_16x16x32_bf16(a, b, c, 0, 0, 0);
}
DEV v8s ld8(const u16* p) { return *(const v8s*)p; }

// ---------------- grid barrier (flag array, agent scope) ----------------
DEV void gbar(u32* flags, int nwg, int wg, u32 tgt) {
  __syncthreads();
  if (threadIdx.x < 64) {
    if (threadIdx.x == 0) {
      __threadfence();
      __hip_atomic_store(flags + wg, tgt, __ATOMIC_RELEASE, __HIP_MEMORY_SCOPE_AGENT);
    }
    const int lane = threadIdx.x;
    for (;;) {
      bool ok = true;
      for (int i = lane; i < nwg; i += 64) {
        u32 v = __hip_atomic_load(flags + i, __ATOMIC_RELAXED, __HIP_MEMORY_SCOPE_AGENT);
        ok &= (v >= tgt);
      }
      if (__ballot((int)ok) == ~0ull) break;
      __builtin_amdgcn_s_sleep(1);
    }
    __threadfence();
  }
  __syncthreads();
}

// ---------------- small utility kernels ----------------
__global__ void k_zero(uint4* p, int n) {
  int i = blockIdx.x * 256 + threadIdx.x;
  if (i < n) p[i] = make_uint4(0, 0, 0, 0);
}

__global__ void k_cvt(const float* __restrict__ s, u16* __restrict__ d, int n) {
  int i = (blockIdx.x * 256 + threadIdx.x) * 4;
  if (i < n) {
    float4 v = *(const float4*)(s + i);
    ushort4 u;
    u.x = f2bf(v.x); u.y = f2bf(v.y); u.z = f2bf(v.z); u.w = f2bf(v.w);
    *(ushort4*)(d + i) = u;
  }
}

// fused [Wih|Whh], 4-granular gate interleave, row-major (LDS-staged by k_rec)
__global__ void k_pack_enc(const float* __restrict__ Wih, const float* __restrict__ Whh,
                           const float* __restrict__ bsrc, u16* __restrict__ Wf,
                           float* __restrict__ bf, int DIN) {
  const int K = DIN + 512;
  const int bx = blockIdx.x;  // 4096
  const int dir = bx >> 11, r = bx & 2047;
  const int g = (r >> 2) & 3, j = ((r >> 4) << 2) | (r & 3);
  const int orig = g * 512 + j;
  const float* wi = Wih + ((size_t)dir * 2048 + orig) * DIN;
  const float* wh = Whh + ((size_t)dir * 2048 + orig) * 512;
  u16* dst = Wf + ((size_t)dir * 2048 + r) * K;
  for (int k = threadIdx.x; k < K; k += 256)
    dst[k] = f2bf(k < DIN ? wi[k] : wh[k - DIN]);
  if (threadIdx.x == 0) bf[dir * 2048 + r] = bsrc[dir * 2048 + orig];
}

// decoder cell weights packed in MFMA B-fragment-major order:
// Wf[wg][kkb][lane=qd*16+l15][8] ; packed row r=wg*16+l15 <- orig gate row
__global__ void k_pack_decf(const float* __restrict__ Wih, const float* __restrict__ Whh,
                            const float* __restrict__ bsrc, u16* __restrict__ Wf,
                            float* __restrict__ bf, int KIN) {
  const int K = KIN + 1024;
  const int r = blockIdx.x;  // 4096
  const int g = (r >> 2) & 3, j = ((r >> 4) << 2) | (r & 3);
  const int orig = g * 1024 + j;
  const float* wi = Wih + (size_t)orig * KIN;
  const float* wh = Whh + (size_t)orig * 1024;
  const int wgi = r >> 4, l15 = r & 15;
  u16* dst = Wf + (size_t)wgi * (size_t)(K >> 5) * 512;
  for (int k = threadIdx.x; k < K; k += 256) {
    float v = k < KIN ? wi[k] : wh[k - KIN];
    dst[(size_t)(k >> 5) * 512 + (((k >> 3) & 3) * 16 + l15) * 8 + (k & 7)] = f2bf(v);
  }
  if (threadIdx.x == 0) bf[r] = bsrc[orig];
}

// WQ[a][c][d] = attnW_a[d][c]  (transposed, bf16)
__global__ void k_pack_attnT(const float* __restrict__ w1, const float* __restrict__ w2,
                             const float* __restrict__ w3, u16* __restrict__ WQ) {
  const int a = blockIdx.x >> 10, tix = blockIdx.x & 1023;
  const int ti = tix >> 5, tj = tix & 31;
  const float* Wsrc = a == 0 ? w1 : (a == 1 ? w2 : w3);
  __shared__ float tl[32][33];
  const int r = threadIdx.x >> 3, c4 = (threadIdx.x & 7) * 4;
  const float* src = Wsrc + (size_t)(ti * 32 + r) * 1024 + tj * 32 + c4;
#pragma unroll
  for (int k = 0; k < 4; ++k) tl[r][c4 + k] = src[k];
  __syncthreads();
  const int cl = threadIdx.x >> 3, d4 = (threadIdx.x & 7) * 4;
  ushort4 u;
  u.x = f2bf(tl[d4 + 0][cl]); u.y = f2bf(tl[d4 + 1][cl]);
  u.z = f2bf(tl[d4 + 2][cl]); u.w = f2bf(tl[d4 + 3][cl]);
  *(ushort4*)(WQ + ((size_t)a << 20) + (size_t)(tj * 32 + cl) * 1024 + ti * 32 + d4) = u;
}

// ---------------- persistent bidirectional LSTM layer ----------------
// grid 256 x 512thr: dir(2) x nt(128): WG owns N=16 packed gate rows = 4 hdims.
// DIN==64: x-part inlined per step. DIN==1024: xg precompute in 8-step chunks.
__global__ __launch_bounds__(512, 1) void k_rec(
    const u16* __restrict__ in, int DIN,
    const u16* __restrict__ Wf, const float* __restrict__ bias,
    u16* __restrict__ XG, u16* __restrict__ hst, u16* __restrict__ outp,
    u32* __restrict__ flags) {
  const int K = DIN + 512;
  const int DINk = DIN >> 5;
  const int wg = blockIdx.x;
  const int dir = wg >> 7, nt = wg & 127;
  const int r0 = nt * 16;
  const int tid = threadIdx.x, w = tid >> 6, lane = tid & 63;
  const int l15 = lane & 15, qd = lane >> 4;

  __shared__ u16 wlds[48 * 512];  // [kkb][lane=qd*16+row][8], up to K=1536
  __shared__ float glds[128][17];

  // stage this WG's 16 weight rows (full K) into LDS fragment layout (once)
  {
    const u16* Wd = Wf + ((size_t)(dir * 2048 + r0)) * K;
    const int cnt = 16 * (K >> 3);
    for (int idx = tid; idx < cnt; idx += 512) {
      const int row = idx & 15, c8 = idx >> 4;
      uint4 v = *(const uint4*)(Wd + (size_t)row * K + c8 * 8);
      *(uint4*)(wlds + ((size_t)(c8 >> 2) * 512 + ((c8 & 3) * 16 + row) * 8)) = v;
    }
  }
  // pointwise mapping + bias regs: thread=(pm=m, jl); WG hdims nt*4+jl
  const int pm = tid >> 2, jl = tid & 3;
  float bw[4];
#pragma unroll
  for (int g = 0; g < 4; ++g) bw[g] = bias[dir * 2048 + r0 + g * 4 + jl];
  float cst = 0.f;
  __syncthreads();

  u32 bt = 1;
  if (DIN == 64) {
    // ---- layer 1: x-part (2 kkb) inlined from global each step ----
    for (int t = 0; t < 256; ++t) {
      const int tt = dir ? (255 - t) : t;
      const int pb = t & 1;
      const u16* xp = in + ((size_t)(w * 16 + l15) * 256 + tt) * 64 + qd * 8;
      const u16* hp = hst + ((size_t)((dir * 2 + pb) * 128 + w * 16 + l15)) * 512 + qd * 8;
      v4f a0 = mfma16(ld8(xp), ld8(wlds + lane * 8), (v4f){0.f, 0.f, 0.f, 0.f});
      v4f a1 = mfma16(ld8(xp + 32), ld8(wlds + 512 + lane * 8), (v4f){0.f, 0.f, 0.f, 0.f});
#pragma unroll 4
      for (int kkb = 0; kkb < 16; kkb += 2) {
        a0 = mfma16(ld8(hp + kkb * 32), ld8(wlds + (2 + kkb) * 512 + lane * 8), a0);
        a1 = mfma16(ld8(hp + kkb * 32 + 32), ld8(wlds + (3 + kkb) * 512 + lane * 8), a1);
      }
#pragma unroll
      for (int r = 0; r < 4; ++r)
        glds[w * 16 + qd * 4 + r][l15] = a0[r] + a1[r];
      __syncthreads();
      {
        float gi = glds[pm][0 * 4 + jl] + bw[0];
        float gf = glds[pm][1 * 4 + jl] + bw[1];
        float gg = glds[pm][2 * 4 + jl] + bw[2];
        float go = glds[pm][3 * 4 + jl] + bw[3];
        float cc = sigm(gf) * cst + sigm(gi) * tanhf(gg);
        cst = cc;
        u16 hb = f2bf(sigm(go) * tanhf(cc));
        hst[((size_t)((dir * 2 + (pb ^ 1)) * 128 + pm)) * 512 + nt * 4 + jl] = hb;
        outp[((size_t)pm * 256 + tt) * 1024 + dir * 512 + nt * 4 + jl] = hb;
      }
      gbar(flags + dir * 128, 128, nt, bt++);
    }
  } else {
    // ---- layer 2: chunks of 8; xg phase (WG-private, no barrier) + 8 rec steps ----
    for (int ch = 0; ch < 32; ++ch) {
      for (int ttl = 0; ttl < 8; ++ttl) {
        const int tt = dir ? (255 - ch * 8 - ttl) : (ch * 8 + ttl);
        const u16* ap = in + ((size_t)(w * 16 + l15) * 256 + tt) * DIN + qd * 8;
        v4f a0 = (v4f){0.f, 0.f, 0.f, 0.f}, a1 = a0;
#pragma unroll 4
        for (int kkb = 0; kkb < 32; kkb += 2) {
          a0 = mfma16(ld8(ap + kkb * 32), ld8(wlds + kkb * 512 + lane * 8), a0);
          a1 = mfma16(ld8(ap + kkb * 32 + 32), ld8(wlds + (kkb + 1) * 512 + lane * 8), a1);
        }
        u16* xo = XG + (((size_t)(dir * 8 + ttl) * 128 + nt) * 128 + w * 16 + qd * 4) * 16 + l15;
#pragma unroll
        for (int r = 0; r < 4; ++r) xo[r * 16] = f2bf(a0[r] + a1[r]);
      }
      for (int ts = 0; ts < 8; ++ts) {
        const int t = ch * 8 + ts;
        const int tt = dir ? (255 - t) : t;
        const int pb = t & 1;
        const u16* hp = hst + ((size_t)((dir * 2 + pb) * 128 + w * 16 + l15)) * 512 + qd * 8;
        v4f a0 = (v4f){0.f, 0.f, 0.f, 0.f}, a1 = a0;
#pragma unroll 4
        for (int kkb = 0; kkb < 16; kkb += 2) {
          a0 = mfma16(ld8(hp + kkb * 32), ld8(wlds + (32 + kkb) * 512 + lane * 8), a0);
          a1 = mfma16(ld8(hp + kkb * 32 + 32), ld8(wlds + (33 + kkb) * 512 + lane * 8), a1);
        }
        const u16* xi = XG + (((size_t)(dir * 8 + ts) * 128 + nt) * 128 + w * 16 + qd * 4) * 16 + l15;
#pragma unroll
        for (int r = 0; r < 4; ++r)
          glds[w * 16 + qd * 4 + r][l15] = a0[r] + a1[r] + bf2f(xi[r * 16]);
        __syncthreads();
        {
          float gi = glds[pm][0 * 4 + jl] + bw[0];
          float gf = glds[pm][1 * 4 + jl] + bw[1];
          float gg = glds[pm][2 * 4 + jl] + bw[2];
          float go = glds[pm][3 * 4 + jl] + bw[3];
          float cc = sigm(gf) * cst + sigm(gi) * tanhf(gg);
          cst = cc;
          u16 hb = f2bf(sigm(go) * tanhf(cc));
          hst[((size_t)((dir * 2 + (pb ^ 1)) * 128 + pm)) * 512 + nt * 4 + jl] = hb;
          outp[((size_t)pm * 256 + tt) * 1024 + dir * 512 + nt * 4 + jl] = hb;
        }
        gbar(flags + dir * 128, 128, nt, bt++);
      }
    }
  }
}

// ---------------- persistent decoder ----------------
struct DecArgs {
  const float *x, *outb;
  float* dout;
  const u16 *eo, *wq, *wout, *wd1, *wd2, *wd3;
  const float *bd1, *bd2, *bd3;
  u16 *qp, *hd, *ad1, *ad2, *ad3;
  u32* flags;
};

union DecSm {
  struct { float glds[128][17]; } c;
  struct {
    u16 e[32][1032];        // single enc chunk, padded stride (~66KB)
    float sbuf[8][16][4];
    float wl[32][4];
    float alpha[4];
    float lfin[4];
  } a;
};

__global__ __launch_bounds__(512, 1) void k_dec(DecArgs A) {
  const int wg = blockIdx.x, tid = threadIdx.x;
  const int w = tid >> 6, lane = tid & 63, l15 = lane & 15, qd = lane >> 4;
  __shared__ DecSm sm;
  u32 bt = 1;

  const int cm_ = tid >> 2, cjl = tid & 3;
  const float* BDs[3] = {A.bd1, A.bd2, A.bd3};
  float cbias[3][4];
#pragma unroll
  for (int ci = 0; ci < 3; ++ci)
#pragma unroll
    for (int g = 0; g < 4; ++g)
      cbias[ci][g] = BDs[ci][wg * 16 + g * 4 + cjl];
  float cstate[3] = {0.f, 0.f, 0.f};

  for (int t = 0; t <= 60; ++t) {
    const int p = t & 1;
    // ---------- P1: q projections (192 WGs), y-proj / prev seed (4 WGs) ----------
    if (wg < 192) {
      const int a = wg / 64, nc0 = (wg & 63) * 16;
      const u16* Ab = A.hd + (size_t)((a * 2 + p) * 128 + w * 16 + l15) * 1024 + qd * 8;
      const u16* Bw = A.wq + ((size_t)a << 20) + (size_t)(nc0 + l15) * 1024 + qd * 8;
      v4f a0 = (v4f){0.f, 0.f, 0.f, 0.f}, a1 = a0;
#pragma unroll 4
      for (int kk = 0; kk < 1024; kk += 64) {
        a0 = mfma16(ld8(Ab + kk), ld8(Bw + kk), a0);
        a1 = mfma16(ld8(Ab + kk + 32), ld8(Bw + kk + 32), a1);
      }
#pragma unroll
      for (int r = 0; r < 4; ++r)
        A.qp[(size_t)(w * 16 + qd * 4 + r) * 16384 + a * 1024 + nc0 + l15] =
            f2bf(a0[r] + a1[r]);
    } else if (wg < 196) {
      const int mt4 = wg - 192;
      if (t == 0) {
        int base = (mt4 * 512 + tid) * 4;
        int b = base >> 6, o = base & 63;
        const float* xs = A.x + (size_t)b * 16384 + 255 * 64 + o;
        u16* dst = A.ad1 + (size_t)b * 2112 + 1024 + o;
#pragma unroll
        for (int k2 = 0; k2 < 4; ++k2) dst[k2] = f2bf(xs[k2]);
      } else {
        const int mb = mt4 * 32 + (w >> 2) * 16, nb = (w & 3) * 16;
        const u16* Ab = A.hd + (size_t)((2 * 2 + p) * 128 + mb + l15) * 1024 + qd * 8;
        const u16* Bw = A.wout + (size_t)(nb + l15) * 1024 + qd * 8;
        v4f a0 = (v4f){0.f, 0.f, 0.f, 0.f}, a1 = a0;
#pragma unroll 4
        for (int kk = 0; kk < 1024; kk += 64) {
          a0 = mfma16(ld8(Ab + kk), ld8(Bw + kk), a0);
          a1 = mfma16(ld8(Ab + kk + 32), ld8(Bw + kk + 32), a1);
        }
        const int o = nb + l15;
        const float bo = A.outb[o];
#pragma unroll
        for (int r = 0; r < 4; ++r) {
          int m = mb + qd * 4 + r;
          float y = a0[r] + a1[r] + bo;
          A.dout[(size_t)m * 3840 + (t - 1) * 64 + o] = y;
          A.ad1[(size_t)m * 2112 + 1024 + o] = f2bf(y);
        }
      }
    }
    gbar(A.flags, 256, wg, bt++);
    if (t == 60) break;

    // ---------- P2: fused 3-head flash attention (128 WGs) + h_old copies ----------
    if (wg < 128) {
      const int b = wg;
      const u16* eob = A.eo + (size_t)b * 256 * 1024;
      v8s qf[8];
      {
        const u16* qsrc = A.qp + (size_t)b * 16384 + (size_t)l15 * 1024 + (w & 3) * 256 + qd * 8;
#pragma unroll
        for (int i = 0; i < 8; ++i) qf[i] = ld8(qsrc + i * 32);
      }
      const int d0 = w * 128 + lane * 2;
      float pv[3][2] = {{0.f, 0.f}, {0.f, 0.f}, {0.f, 0.f}};
      float mml0 = -3e38f, mml1 = -3e38f, mml2 = -3e38f;
      float lll0 = 0.f, lll1 = 0.f, lll2 = 0.f;
      const int sr = tid >> 4, sc = (tid & 15) * 8;
      // stage chunk 0
#pragma unroll
      for (int i = 0; i < 8; ++i)
        *(uint4*)&sm.a.e[sr][sc + i * 128] =
            *(const uint4*)(eob + (size_t)sr * 1024 + sc + i * 128);
      __syncthreads();

      for (int c = 0; c < 8; ++c) {
        // issue next-chunk prefetch early (latency overlaps scores+softmax+PV)
        uint4 pf[8];
        if (c < 7) {
          const u16* src = eob + (size_t)((c + 1) * 32 + sr) * 1024 + sc;
#pragma unroll
          for (int i = 0; i < 8; ++i) pf[i] = *(const uint4*)(src + i * 128);
        }
        // scores: wave (rows (w>>2)*16, K-quarter w&3) from LDS
        {
          v4f sa = (v4f){0.f, 0.f, 0.f, 0.f};
          const u16* eb = &sm.a.e[(w >> 2) * 16 + l15][(w & 3) * 256 + qd * 8];
#pragma unroll
          for (int i = 0; i < 8; ++i) sa = mfma16(qf[i], ld8(eb + i * 32), sa);
          if (lane < 16) *(v4f*)&sm.a.sbuf[w][lane][0] = sa;
        }
        __syncthreads();
        // online softmax (one half-wave)
        if (tid < 32) {
          const int s = tid, sbb = s >> 4, sl = s & 15;
          float sc0 = 0.f, sc1 = 0.f, sc2 = 0.f;
#pragma unroll
          for (int k = 0; k < 4; ++k) {
            const float* sp = &sm.a.sbuf[sbb * 4 + k][sl][0];
            sc0 += sp[0]; sc1 += sp[1]; sc2 += sp[2];
          }
          float c0 = sc0, c1 = sc1, c2 = sc2;
#pragma unroll
          for (int m = 16; m >= 1; m >>= 1) {
            c0 = fmaxf(c0, __shfl_xor(c0, m));
            c1 = fmaxf(c1, __shfl_xor(c1, m));
            c2 = fmaxf(c2, __shfl_xor(c2, m));
          }
          float n0 = fmaxf(mml0, c0), n1 = fmaxf(mml1, c1), n2 = fmaxf(mml2, c2);
          float a0 = __expf(mml0 - n0), a1 = __expf(mml1 - n1), a2 = __expf(mml2 - n2);
          mml0 = n0; mml1 = n1; mml2 = n2;
          float w0 = __expf(sc0 - n0), w1 = __expf(sc1 - n1), w2 = __expf(sc2 - n2);
          sm.a.wl[s][0] = w0; sm.a.wl[s][1] = w1; sm.a.wl[s][2] = w2;
          float t0 = w0, t1 = w1, t2 = w2;
#pragma unroll
          for (int m = 16; m >= 1; m >>= 1) {
            t0 += __shfl_xor(t0, m); t1 += __shfl_xor(t1, m); t2 += __shfl_xor(t2, m);
          }
          lll0 = lll0 * a0 + t0; lll1 = lll1 * a1 + t1; lll2 = lll2 * a2 + t2;
          if (s == 0) {
            sm.a.alpha[0] = a0; sm.a.alpha[1] = a1; sm.a.alpha[2] = a2;
            sm.a.lfin[0] = lll0; sm.a.lfin[1] = lll1; sm.a.lfin[2] = lll2;
          }
        }
        __syncthreads();
        // PV: lane's 2 dims over the 32 rows (LDS broadcast weights)
        {
          const float a0 = sm.a.alpha[0], a1 = sm.a.alpha[1], a2 = sm.a.alpha[2];
          pv[0][0] *= a0; pv[0][1] *= a0;
          pv[1][0] *= a1; pv[1][1] *= a1;
          pv[2][0] *= a2; pv[2][1] *= a2;
#pragma unroll 4
          for (int s = 0; s < 32; ++s) {
            const float w0 = sm.a.wl[s][0], w1 = sm.a.wl[s][1], w2 = sm.a.wl[s][2];
            u32 ee = *(const u32*)&sm.a.e[s][d0];
            float e0 = bf2f((u16)ee), e1 = bf2f((u16)(ee >> 16));
            pv[0][0] += w0 * e0; pv[0][1] += w0 * e1;
            pv[1][0] += w1 * e0; pv[1][1] += w1 * e1;
            pv[2][0] += w2 * e0; pv[2][1] += w2 * e1;
          }
        }
        __syncthreads();  // all PV reads of e done
        if (c < 7) {
#pragma unroll
          for (int i = 0; i < 8; ++i)
            *(uint4*)&sm.a.e[sr][sc + i * 128] = pf[i];
        }
        __syncthreads();  // e ready for next scores
      }
      // finalize ctx -> cell A-staging (lane owns dims d0,d0+1 exclusively)
      {
        const float il0 = 1.0f / sm.a.lfin[0], il1 = 1.0f / sm.a.lfin[1],
                    il2 = 1.0f / sm.a.lfin[2];
        u32 p0 = (u32)f2bf(pv[0][0] * il0) | ((u32)f2bf(pv[0][1] * il0) << 16);
        u32 p1 = (u32)f2bf(pv[1][0] * il1) | ((u32)f2bf(pv[1][1] * il1) << 16);
        u32 p2 = (u32)f2bf(pv[2][0] * il2) | ((u32)f2bf(pv[2][1] * il2) << 16);
        *(u32*)&A.ad1[(size_t)b * 2112 + d0] = p0;
        *(u32*)&A.ad2[(size_t)b * 3072 + d0] = p1;
        *(u32*)&A.ad3[(size_t)b * 3072 + d0] = p2;
      }
    } else {
      // WGs 128..255: copy h_old segments into cell A-staging
      const int b = wg - 128;
      const u16* h1 = A.hd + (size_t)((0 * 2 + p) * 128 + b) * 1024;
      const u16* h2 = A.hd + (size_t)((1 * 2 + p) * 128 + b) * 1024;
      const u16* h3 = A.hd + (size_t)((2 * 2 + p) * 128 + b) * 1024;
      if (tid < 128) {
        *(uint4*)(A.ad1 + (size_t)b * 2112 + 1088 + tid * 8) = *(const uint4*)(h1 + tid * 8);
      } else if (tid < 256) {
        int c8 = tid - 128;
        *(uint4*)(A.ad2 + (size_t)b * 3072 + 2048 + c8 * 8) = *(const uint4*)(h2 + c8 * 8);
      } else if (tid < 384) {
        int c8 = tid - 256;
        *(uint4*)(A.ad3 + (size_t)b * 3072 + 2048 + c8 * 8) = *(const uint4*)(h3 + c8 * 8);
      }
    }
    gbar(A.flags, 256, wg, bt++);

    // ---------- cells 1..3: GEMM (B-frags from global, fragment-packed) + pointwise ----------
#pragma unroll
    for (int ci = 0; ci < 3; ++ci) {
      const int Kc = (ci == 0) ? 2112 : 3072;
      const u16* wb = (ci == 0 ? A.wd1 : ci == 1 ? A.wd2 : A.wd3) +
                      (size_t)wg * (size_t)(Kc >> 5) * 512;
      const u16* Ac = (ci == 0 ? A.ad1 : ci == 1 ? A.ad2 : A.ad3);
      {
        const u16* Ab = Ac + (size_t)(w * 16 + l15) * Kc + qd * 8;
        v4f a0 = (v4f){0.f, 0.f, 0.f, 0.f}, a1 = a0;
        const int NKB = Kc >> 5;
#pragma unroll 4
        for (int kkb = 0; kkb < NKB; kkb += 2) {
          a0 = mfma16(ld8(Ab + kkb * 32), ld8(wb + kkb * 512 + lane * 8), a0);
          a1 = mfma16(ld8(Ab + kkb * 32 + 32), ld8(wb + (kkb + 1) * 512 + lane * 8), a1);
        }
#pragma unroll
        for (int r = 0; r < 4; ++r)
          sm.c.glds[w * 16 + qd * 4 + r][l15] = a0[r] + a1[r];
      }
      __syncthreads();
      {
        float gi = sm.c.glds[cm_][0 * 4 + cjl] + cbias[ci][0];
        float gf = sm.c.glds[cm_][1 * 4 + cjl] + cbias[ci][1];
        float gg = sm.c.glds[cm_][2 * 4 + cjl] + cbias[ci][2];
        float go = sm.c.glds[cm_][3 * 4 + cjl] + cbias[ci][3];
        float cv = sigm(gf) * cstate[ci] + sigm(gi) * tanhf(gg);
        cstate[ci] = cv;
        u16 hb = f2bf(sigm(go) * tanhf(cv));
        const int jg = wg * 4 + cjl;
        A.hd[(size_t)((ci * 2 + (p ^ 1)) * 128 + cm_) * 1024 + jg] = hb;
        if (ci == 0) A.ad2[(size_t)cm_ * 3072 + 1024 + jg] = hb;
        else if (ci == 1) A.ad3[(size_t)cm_ * 3072 + 1024 + jg] = hb;
      }
      gbar(A.flags, 256, wg, bt++);
    }
  }
}

// ---------------- host ----------------
extern "C" void kernel_launch(void* const* d_in, const int* in_sizes, int n_in,
                              void* d_out, int out_size, void* d_ws, size_t ws_size,
                              hipStream_t stream) {
  char* ws = (char*)d_ws;
  size_t off = 0;
  auto alc = [&](size_t bytes) -> char* {
    char* pp = ws + off;
    off += (bytes + 255) & ~(size_t)255;
    return pp;
  };
  u16* XB = (u16*)alc(2097152ull * 2);
  u16* WF0 = (u16*)alc(2359296ull * 2);
  float* BF0 = (float*)alc(4096ull * 4);
  u16* WF1 = (u16*)alc(6291456ull * 2);
  float* BF1 = (float*)alc(4096ull * 4);
  u16* H0 = (u16*)alc(33554432ull * 2);
  u16* EO = (u16*)alc(33554432ull * 2);
  u16* HS0 = (u16*)alc(262144ull * 2);
  u16* HS1 = (u16*)alc(262144ull * 2);
  u16* XG = (u16*)alc(4194304ull * 2);   // [dir][8][nt 128][m 128][16] chunk buffer (8.4MB)
  u16* WQ = (u16*)alc(3145728ull * 2);
  u16* WOUT = (u16*)alc(65536ull * 2);
  u16* WD1 = (u16*)alc(8650752ull * 2);
  float* BD1 = (float*)alc(4096ull * 4);
  u16* WD2 = (u16*)alc(12582912ull * 2);
  float* BD2 = (float*)alc(4096ull * 4);
  u16* WD3 = (u16*)alc(12582912ull * 2);
  float* BD3 = (float*)alc(4096ull * 4);
  u16* QP = (u16*)alc(2097152ull * 2);
  u16* HD = (u16*)alc(786432ull * 2);
  u16* AD1 = (u16*)alc(270336ull * 2);
  u16* AD2 = (u16*)alc(393216ull * 2);
  u16* AD3 = (u16*)alc(393216ull * 2);
  u32* FLAGS = (u32*)alc(1536ull * 4);

  // zero state buffers (ws is poisoned before every call)
  k_zero<<<2, 256, 0, stream>>>((uint4*)FLAGS, 384);
  k_zero<<<1024, 256, 0, stream>>>((uint4*)QP, 262144);
  k_zero<<<128, 256, 0, stream>>>((uint4*)HS0, 32768);
  k_zero<<<128, 256, 0, stream>>>((uint4*)HS1, 32768);
  k_zero<<<384, 256, 0, stream>>>((uint4*)HD, 98304);

  // pack weights / inputs to bf16
  k_cvt<<<2048, 256, 0, stream>>>((const float*)d_in[0], XB, 2097152);
  k_cvt<<<64, 256, 0, stream>>>((const float*)d_in[22], WOUT, 65536);
  k_pack_enc<<<4096, 256, 0, stream>>>((const float*)d_in[1], (const float*)d_in[2],
                                       (const float*)d_in[3], WF0, BF0, 64);
  k_pack_enc<<<4096, 256, 0, stream>>>((const float*)d_in[4], (const float*)d_in[5],
                                       (const float*)d_in[6], WF1, BF1, 1024);
  k_pack_attnT<<<3072, 256, 0, stream>>>((const float*)d_in[7], (const float*)d_in[9],
                                         (const float*)d_in[11], WQ);
  k_pack_decf<<<4096, 256, 0, stream>>>((const float*)d_in[13], (const float*)d_in[14],
                                        (const float*)d_in[15], WD1, BD1, 1088);
  k_pack_decf<<<4096, 256, 0, stream>>>((const float*)d_in[16], (const float*)d_in[17],
                                        (const float*)d_in[18], WD2, BD2, 2048);
  k_pack_decf<<<4096, 256, 0, stream>>>((const float*)d_in[19], (const float*)d_in[20],
                                        (const float*)d_in[21], WD3, BD3, 2048);

  // encoder layers (persistent, 256 WGs x 512 threads each)
  k_rec<<<256, 512, 0, stream>>>(XB, 64, WF0, BF0, XG, HS0, H0, FLAGS);
  k_rec<<<256, 512, 0, stream>>>(H0, 1024, WF1, BF1, XG, HS1, EO, FLAGS + 256);

  // decoder (persistent, 256 WGs x 512 threads)
  DecArgs da;
  da.x = (const float*)d_in[0];
  da.outb = (const float*)d_in[23];
  da.dout = (float*)d_out;
  da.eo = EO; da.wq = WQ; da.wout = WOUT;
  da.wd1 = WD1; da.wd2 = WD2; da.wd3 = WD3;
  da.bd1 = BD1; da.bd2 = BD2; da.bd3 = BD3;
  da.qp = QP; da.hd = HD; da.ad1 = AD1; da.ad2 = AD2; da.ad3 = AD3;
  da.flags = FLAGS + 512;
  k_dec<<<256, 512, 0, stream>>>(da);
}

// Round 5
// 25045.284 us; speedup vs baseline: 1.1967x; 1.1967x over previous
//
#include <hip/hip_runtime.h>

typedef unsigned short u16;
typedef unsigned int u32;
typedef unsigned long long u64;
typedef short v8s __attribute__((ext_vector_type(8)));
typedef float v4f __attribute__((ext_vector_type(4)));

#define DEV static __device__ __forceinline__

DEV float bf2f(u16 u) { union { u32 i; float f; } v; v.i = ((u32)u) << 16; return v.f; }
DEV u16 f2bf(float f) {
  union { float f; u32 i; } v; v.f = f;
  u32 i = v.i + 0x7FFFu + ((v.i >> 16) & 1u);
  return (u16)(i >> 16);
}
DEV float sigm(float x) { return 1.0f / (1.0f + __expf(-x)); }
DEV v4f mfma16(v8s a, v8s b, v4f c) {
  return __builtin_amdgcn_mfma_f32_16x16x32_bf16(a, b, c, 0, 0, 0);
}
DEV v8s ld8(const u16* p) { return *(const v8s*)p; }

// ---- coherent (write-through / L2-bypass) accessors for cross-WG data ----
DEV u64 ldg64(const u16* p) {
  return __hip_atomic_load((const u64*)p, __ATOMIC_RELAXED, __HIP_MEMORY_SCOPE_AGENT);
}
DEV void stg32(u16* p, u32 v) {
  __hip_atomic_store((u32*)p, v, __ATOMIC_RELAXED, __HIP_MEMORY_SCOPE_AGENT);
}
DEV void stg64(u16* p, u64 v) {
  __hip_atomic_store((u64*)p, v, __ATOMIC_RELAXED, __HIP_MEMORY_SCOPE_AGENT);
}
DEV v8s ld8c(const u16* p) {
  union { u64 q[2]; v8s v; } u;
  u.q[0] = ldg64(p);
  u.q[1] = ldg64(p + 4);
  return u.v;
}

// ---------------- fence-free grid barrier ----------------
// Correctness: all cross-WG data uses write-through atomic stores; __syncthreads
// drains vmcnt (stores complete at L3) before the flag release; readers bypass L2.
DEV void gbar(u32* flags, int nwg, int wg, u32 tgt) {
  __syncthreads();
  if (threadIdx.x == 0)
    __hip_atomic_store(flags + wg, tgt, __ATOMIC_RELAXED, __HIP_MEMORY_SCOPE_AGENT);
  if (threadIdx.x < 64) {
    const int lane = threadIdx.x;
    for (;;) {
      bool ok = true;
      for (int i = lane; i < nwg; i += 64) {
        u32 v = __hip_atomic_load(flags + i, __ATOMIC_RELAXED, __HIP_MEMORY_SCOPE_AGENT);
        ok &= (v >= tgt);
      }
      if (__ballot((int)ok) == ~0ull) break;
      __builtin_amdgcn_s_sleep(1);
    }
  }
  __syncthreads();
}

// ---------------- small utility kernels ----------------
__global__ void k_zero(uint4* p, int n) {
  int i = blockIdx.x * 256 + threadIdx.x;
  if (i < n) p[i] = make_uint4(0, 0, 0, 0);
}

__global__ void k_cvt(const float* __restrict__ s, u16* __restrict__ d, int n) {
  int i = (blockIdx.x * 256 + threadIdx.x) * 4;
  if (i < n) {
    float4 v = *(const float4*)(s + i);
    ushort4 u;
    u.x = f2bf(v.x); u.y = f2bf(v.y); u.z = f2bf(v.z); u.w = f2bf(v.w);
    *(ushort4*)(d + i) = u;
  }
}

// fused [Wih|Whh], 4-granular gate interleave, row-major (LDS-staged by k_rec)
__global__ void k_pack_enc(const float* __restrict__ Wih, const float* __restrict__ Whh,
                           const float* __restrict__ bsrc, u16* __restrict__ Wf,
                           float* __restrict__ bf, int DIN) {
  const int K = DIN + 512;
  const int bx = blockIdx.x;  // 4096
  const int dir = bx >> 11, r = bx & 2047;
  const int g = (r >> 2) & 3, j = ((r >> 4) << 2) | (r & 3);
  const int orig = g * 512 + j;
  const float* wi = Wih + ((size_t)dir * 2048 + orig) * DIN;
  const float* wh = Whh + ((size_t)dir * 2048 + orig) * 512;
  u16* dst = Wf + ((size_t)dir * 2048 + r) * K;
  for (int k = threadIdx.x; k < K; k += 256)
    dst[k] = f2bf(k < DIN ? wi[k] : wh[k - DIN]);
  if (threadIdx.x == 0) bf[dir * 2048 + r] = bsrc[dir * 2048 + orig];
}

// decoder cell weights packed in MFMA B-fragment-major order:
// Wf[wg][kkb][lane=qd*16+l15][8] ; packed row r=wg*16+l15 <- orig gate row
__global__ void k_pack_decf(const float* __restrict__ Wih, const float* __restrict__ Whh,
                            const float* __restrict__ bsrc, u16* __restrict__ Wf,
                            float* __restrict__ bf, int KIN) {
  const int K = KIN + 1024;
  const int r = blockIdx.x;  // 4096
  const int g = (r >> 2) & 3, j = ((r >> 4) << 2) | (r & 3);
  const int orig = g * 1024 + j;
  const float* wi = Wih + (size_t)orig * KIN;
  const float* wh = Whh + (size_t)orig * 1024;
  const int wgi = r >> 4, l15 = r & 15;
  u16* dst = Wf + (size_t)wgi * (size_t)(K >> 5) * 512;
  for (int k = threadIdx.x; k < K; k += 256) {
    float v = k < KIN ? wi[k] : wh[k - KIN];
    dst[(size_t)(k >> 5) * 512 + (((k >> 3) & 3) * 16 + l15) * 8 + (k & 7)] = f2bf(v);
  }
  if (threadIdx.x == 0) bf[r] = bsrc[orig];
}

// WQ[a][c][d] = attnW_a[d][c]  (transposed, bf16)
__global__ void k_pack_attnT(const float* __restrict__ w1, const float* __restrict__ w2,
                             const float* __restrict__ w3, u16* __restrict__ WQ) {
  const int a = blockIdx.x >> 10, tix = blockIdx.x & 1023;
  const int ti = tix >> 5, tj = tix & 31;
  const float* Wsrc = a == 0 ? w1 : (a == 1 ? w2 : w3);
  __shared__ float tl[32][33];
  const int r = threadIdx.x >> 3, c4 = (threadIdx.x & 7) * 4;
  const float* src = Wsrc + (size_t)(ti * 32 + r) * 1024 + tj * 32 + c4;
#pragma unroll
  for (int k = 0; k < 4; ++k) tl[r][c4 + k] = src[k];
  __syncthreads();
  const int cl = threadIdx.x >> 3, d4 = (threadIdx.x & 7) * 4;
  ushort4 u;
  u.x = f2bf(tl[d4 + 0][cl]); u.y = f2bf(tl[d4 + 1][cl]);
  u.z = f2bf(tl[d4 + 2][cl]); u.w = f2bf(tl[d4 + 3][cl]);
  *(ushort4*)(WQ + ((size_t)a << 20) + (size_t)(tj * 32 + cl) * 1024 + ti * 32 + d4) = u;
}

// ---------------- persistent bidirectional LSTM layer ----------------
// grid 256 x 512thr: dir(2) x nt(128): WG owns N=16 packed gate rows = 4 hdims.
// DIN==64: x-part inlined per step. DIN==1024: xg precompute in 8-step chunks.
__global__ __launch_bounds__(512, 1) void k_rec(
    const u16* __restrict__ in, int DIN,
    const u16* __restrict__ Wf, const float* __restrict__ bias,
    u16* __restrict__ XG, u16* __restrict__ hst, u16* __restrict__ outp,
    u32* __restrict__ flags) {
  const int K = DIN + 512;
  const int wg = blockIdx.x;
  const int dir = wg >> 7, nt = wg & 127;
  const int r0 = nt * 16;
  const int tid = threadIdx.x, w = tid >> 6, lane = tid & 63;
  const int l15 = lane & 15, qd = lane >> 4;

  __shared__ u16 wlds[48 * 512];  // [kkb][lane=qd*16+row][8], up to K=1536
  __shared__ float glds[128][17];

  // stage this WG's 16 weight rows (full K) into LDS fragment layout (once)
  {
    const u16* Wd = Wf + ((size_t)(dir * 2048 + r0)) * K;
    const int cnt = 16 * (K >> 3);
    for (int idx = tid; idx < cnt; idx += 512) {
      const int row = idx & 15, c8 = idx >> 4;
      uint4 v = *(const uint4*)(Wd + (size_t)row * K + c8 * 8);
      *(uint4*)(wlds + ((size_t)(c8 >> 2) * 512 + ((c8 & 3) * 16 + row) * 8)) = v;
    }
  }
  // pointwise mapping + bias regs: thread(tid<256)=(m=tid>>1, jpair=tid&1)
  const int pm = tid >> 1, jp = tid & 1;
  float bw[4][2];
#pragma unroll
  for (int g = 0; g < 4; ++g)
#pragma unroll
    for (int jj = 0; jj < 2; ++jj)
      bw[g][jj] = bias[dir * 2048 + r0 + g * 4 + jp * 2 + jj];
  float cst[2] = {0.f, 0.f};
  __syncthreads();

  u32 bt = 1;
  if (DIN == 64) {
    // ---- layer 1: x-part (2 kkb) inlined from global each step ----
    for (int t = 0; t < 256; ++t) {
      const int tt = dir ? (255 - t) : t;
      const int pb = t & 1;
      const u16* xp = in + ((size_t)(w * 16 + l15) * 256 + tt) * 64 + qd * 8;
      const u16* hp = hst + ((size_t)((dir * 2 + pb) * 128 + w * 16 + l15)) * 512 + qd * 8;
      v4f a0 = mfma16(ld8(xp), ld8(wlds + lane * 8), (v4f){0.f, 0.f, 0.f, 0.f});
      v4f a1 = mfma16(ld8(xp + 32), ld8(wlds + 512 + lane * 8), (v4f){0.f, 0.f, 0.f, 0.f});
#pragma unroll 4
      for (int kkb = 0; kkb < 16; kkb += 2) {
        a0 = mfma16(ld8c(hp + kkb * 32), ld8(wlds + (2 + kkb) * 512 + lane * 8), a0);
        a1 = mfma16(ld8c(hp + kkb * 32 + 32), ld8(wlds + (3 + kkb) * 512 + lane * 8), a1);
      }
#pragma unroll
      for (int r = 0; r < 4; ++r)
        glds[w * 16 + qd * 4 + r][l15] = a0[r] + a1[r];
      __syncthreads();
      if (tid < 256) {
        float hv2[2];
#pragma unroll
        for (int jj = 0; jj < 2; ++jj) {
          const int jl = jp * 2 + jj;
          float gi = glds[pm][0 * 4 + jl] + bw[0][jj];
          float gf = glds[pm][1 * 4 + jl] + bw[1][jj];
          float gg = glds[pm][2 * 4 + jl] + bw[2][jj];
          float go = glds[pm][3 * 4 + jl] + bw[3][jj];
          float cc = sigm(gf) * cst[jj] + sigm(gi) * tanhf(gg);
          cst[jj] = cc;
          hv2[jj] = sigm(go) * tanhf(cc);
        }
        u32 hv = (u32)f2bf(hv2[0]) | ((u32)f2bf(hv2[1]) << 16);
        stg32(hst + ((size_t)((dir * 2 + (pb ^ 1)) * 128 + pm)) * 512 + nt * 4 + jp * 2, hv);
        *(u32*)(outp + ((size_t)pm * 256 + tt) * 1024 + dir * 512 + nt * 4 + jp * 2) = hv;
      }
      gbar(flags + dir * 128, 128, nt, bt++);
    }
  } else {
    // ---- layer 2: chunks of 8; xg phase (WG-private, no barrier) + 8 rec steps ----
    for (int ch = 0; ch < 32; ++ch) {
      for (int ttl = 0; ttl < 8; ++ttl) {
        const int tt = dir ? (255 - ch * 8 - ttl) : (ch * 8 + ttl);
        const u16* ap = in + ((size_t)(w * 16 + l15) * 256 + tt) * 1024 + qd * 8;
        v4f a0 = (v4f){0.f, 0.f, 0.f, 0.f}, a1 = a0;
#pragma unroll 4
        for (int kkb = 0; kkb < 32; kkb += 2) {
          a0 = mfma16(ld8(ap + kkb * 32), ld8(wlds + kkb * 512 + lane * 8), a0);
          a1 = mfma16(ld8(ap + kkb * 32 + 32), ld8(wlds + (kkb + 1) * 512 + lane * 8), a1);
        }
        u16* xo = XG + (((size_t)(dir * 8 + ttl) * 128 + nt) * 128 + w * 16 + qd * 4) * 16 + l15;
#pragma unroll
        for (int r = 0; r < 4; ++r) xo[r * 16] = f2bf(a0[r] + a1[r]);
      }
      for (int ts = 0; ts < 8; ++ts) {
        const int t = ch * 8 + ts;
        const int tt = dir ? (255 - t) : t;
        const int pb = t & 1;
        const u16* hp = hst + ((size_t)((dir * 2 + pb) * 128 + w * 16 + l15)) * 512 + qd * 8;
        v4f a0 = (v4f){0.f, 0.f, 0.f, 0.f}, a1 = a0;
#pragma unroll 4
        for (int kkb = 0; kkb < 16; kkb += 2) {
          a0 = mfma16(ld8c(hp + kkb * 32), ld8(wlds + (32 + kkb) * 512 + lane * 8), a0);
          a1 = mfma16(ld8c(hp + kkb * 32 + 32), ld8(wlds + (33 + kkb) * 512 + lane * 8), a1);
        }
        const u16* xi = XG + (((size_t)(dir * 8 + ts) * 128 + nt) * 128 + w * 16 + qd * 4) * 16 + l15;
#pragma unroll
        for (int r = 0; r < 4; ++r)
          glds[w * 16 + qd * 4 + r][l15] = a0[r] + a1[r] + bf2f(xi[r * 16]);
        __syncthreads();
        if (tid < 256) {
          float hv2[2];
#pragma unroll
          for (int jj = 0; jj < 2; ++jj) {
            const int jl = jp * 2 + jj;
            float gi = glds[pm][0 * 4 + jl] + bw[0][jj];
            float gf = glds[pm][1 * 4 + jl] + bw[1][jj];
            float gg = glds[pm][2 * 4 + jl] + bw[2][jj];
            float go = glds[pm][3 * 4 + jl] + bw[3][jj];
            float cc = sigm(gf) * cst[jj] + sigm(gi) * tanhf(gg);
            cst[jj] = cc;
            hv2[jj] = sigm(go) * tanhf(cc);
          }
          u32 hv = (u32)f2bf(hv2[0]) | ((u32)f2bf(hv2[1]) << 16);
          stg32(hst + ((size_t)((dir * 2 + (pb ^ 1)) * 128 + pm)) * 512 + nt * 4 + jp * 2, hv);
          *(u32*)(outp + ((size_t)pm * 256 + tt) * 1024 + dir * 512 + nt * 4 + jp * 2) = hv;
        }
        gbar(flags + dir * 128, 128, nt, bt++);
      }
    }
  }
}

// ---------------- persistent decoder ----------------
struct DecArgs {
  const float *x, *outb;
  float* dout;
  const u16 *eo, *wq, *wout, *wd1, *wd2, *wd3;
  const float *bd1, *bd2, *bd3;
  u16 *qp, *hd, *ad1, *ad2, *ad3;
  u32* flags;
};

union DecSm {
  struct { float glds[128][17]; } c;   // cell / P1 C-staging
  struct { float yb[32][65]; } y;      // yproj C-staging
  struct {
    u16 e[32][1032];        // single enc chunk, padded stride (~66KB)
    float sbuf[8][16][4];
    float wl[32][4];
    float alpha[4];
    float lfin[4];
  } a;
};

__global__ __launch_bounds__(512, 1) void k_dec(DecArgs A) {
  const int wg = blockIdx.x, tid = threadIdx.x;
  const int w = tid >> 6, lane = tid & 63, l15 = lane & 15, qd = lane >> 4;
  __shared__ DecSm sm;
  u32 bt = 1;

  // cell pointwise: thread(tid<256) = (m=tid>>1, jpair=tid&1); WG hdims wg*4..+4
  const int cm_ = tid >> 1, cjp = tid & 1;
  const float* BDs[3] = {A.bd1, A.bd2, A.bd3};
  float cbias[3][4][2];
#pragma unroll
  for (int ci = 0; ci < 3; ++ci)
#pragma unroll
    for (int g = 0; g < 4; ++g)
#pragma unroll
      for (int jj = 0; jj < 2; ++jj)
        cbias[ci][g][jj] = BDs[ci][wg * 16 + g * 4 + cjp * 2 + jj];
  float cstate[3][2] = {{0.f, 0.f}, {0.f, 0.f}, {0.f, 0.f}};

  for (int t = 0; t <= 60; ++t) {
    const int p = t & 1;
    // ---------- P1: q projections (192 WGs), y-proj / prev seed (4 WGs) ----------
    if (wg < 192) {
      const int a = wg / 64, nc0 = (wg & 63) * 16;
      const u16* Ab = A.hd + (size_t)((a * 2 + p) * 128 + w * 16 + l15) * 1024 + qd * 8;
      const u16* Bw = A.wq + ((size_t)a << 20) + (size_t)(nc0 + l15) * 1024 + qd * 8;
      v4f a0 = (v4f){0.f, 0.f, 0.f, 0.f}, a1 = a0;
#pragma unroll 4
      for (int kk = 0; kk < 1024; kk += 64) {
        a0 = mfma16(ld8c(Ab + kk), ld8(Bw + kk), a0);
        a1 = mfma16(ld8c(Ab + kk + 32), ld8(Bw + kk + 32), a1);
      }
#pragma unroll
      for (int r = 0; r < 4; ++r)
        sm.c.glds[w * 16 + qd * 4 + r][l15] = a0[r] + a1[r];
      __syncthreads();
      {
        const int m = tid >> 2, c4 = (tid & 3) * 4;
        const float* row = &sm.c.glds[m][0];
        u32 lo = (u32)f2bf(row[c4]) | ((u32)f2bf(row[c4 + 1]) << 16);
        u32 hi = (u32)f2bf(row[c4 + 2]) | ((u32)f2bf(row[c4 + 3]) << 16);
        u16* qdst = A.qp + (size_t)m * 16384 + a * 1024 + nc0 + c4;
        stg32(qdst, lo);
        stg32(qdst + 2, hi);
      }
    } else if (wg < 196) {
      const int mt4 = wg - 192;
      if (t == 0) {
        int base = (mt4 * 512 + tid) * 4;
        int b = base >> 6, o = base & 63;
        const float* xs = A.x + (size_t)b * 16384 + 255 * 64 + o;
        u16* dst = A.ad1 + (size_t)b * 2112 + 1024 + o;
        stg32(dst, (u32)f2bf(xs[0]) | ((u32)f2bf(xs[1]) << 16));
        stg32(dst + 2, (u32)f2bf(xs[2]) | ((u32)f2bf(xs[3]) << 16));
      } else {
        const int mb = mt4 * 32 + (w >> 2) * 16, nb = (w & 3) * 16;
        const u16* Ab = A.hd + (size_t)((2 * 2 + p) * 128 + mb + l15) * 1024 + qd * 8;
        const u16* Bw = A.wout + (size_t)(nb + l15) * 1024 + qd * 8;
        v4f a0 = (v4f){0.f, 0.f, 0.f, 0.f}, a1 = a0;
#pragma unroll 4
        for (int kk = 0; kk < 1024; kk += 64) {
          a0 = mfma16(ld8c(Ab + kk), ld8(Bw + kk), a0);
          a1 = mfma16(ld8c(Ab + kk + 32), ld8(Bw + kk + 32), a1);
        }
        const int mloc = (w >> 2) * 16 + qd * 4;
#pragma unroll
        for (int r = 0; r < 4; ++r)
          sm.y.yb[mloc + r][nb + l15] = a0[r] + a1[r] + A.outb[nb + l15];
        __syncthreads();
        {
          const int ml = tid >> 4, c4 = (tid & 15) * 4;
          const int mg = mt4 * 32 + ml;
          float y0 = sm.y.yb[ml][c4], y1 = sm.y.yb[ml][c4 + 1];
          float y2 = sm.y.yb[ml][c4 + 2], y3 = sm.y.yb[ml][c4 + 3];
          float4 yv = {y0, y1, y2, y3};
          *(float4*)(A.dout + (size_t)mg * 3840 + (t - 1) * 64 + c4) = yv;
          u16* dst = A.ad1 + (size_t)mg * 2112 + 1024 + c4;
          stg32(dst, (u32)f2bf(y0) | ((u32)f2bf(y1) << 16));
          stg32(dst + 2, (u32)f2bf(y2) | ((u32)f2bf(y3) << 16));
        }
      }
    }
    gbar(A.flags, 256, wg, bt++);
    if (t == 60) break;

    // ---------- P2: fused 3-head flash attention (128 WGs) + h_old copies ----------
    if (wg < 128) {
      const int b = wg;
      const u16* eob = A.eo + (size_t)b * 256 * 1024;
      v8s qf[8];
      {
        const u16* qsrc = A.qp + (size_t)b * 16384 + (size_t)l15 * 1024 + (w & 3) * 256 + qd * 8;
#pragma unroll
        for (int i = 0; i < 8; ++i) qf[i] = ld8c(qsrc + i * 32);
      }
      const int d0 = w * 128 + lane * 2;
      float pv[3][2] = {{0.f, 0.f}, {0.f, 0.f}, {0.f, 0.f}};
      float mml0 = -3e38f, mml1 = -3e38f, mml2 = -3e38f;
      float lll0 = 0.f, lll1 = 0.f, lll2 = 0.f;
      const int sr = tid >> 4, sc = (tid & 15) * 8;
      // stage chunk 0 (eo is kernel-static: plain cached loads)
#pragma unroll
      for (int i = 0; i < 8; ++i)
        *(uint4*)&sm.a.e[sr][sc + i * 128] =
            *(const uint4*)(eob + (size_t)sr * 1024 + sc + i * 128);
      __syncthreads();

      for (int c = 0; c < 8; ++c) {
        uint4 pf[8];
        if (c < 7) {
          const u16* src = eob + (size_t)((c + 1) * 32 + sr) * 1024 + sc;
#pragma unroll
          for (int i = 0; i < 8; ++i) pf[i] = *(const uint4*)(src + i * 128);
        }
        {
          v4f sa = (v4f){0.f, 0.f, 0.f, 0.f};
          const u16* eb = &sm.a.e[(w >> 2) * 16 + l15][(w & 3) * 256 + qd * 8];
#pragma unroll
          for (int i = 0; i < 8; ++i) sa = mfma16(qf[i], ld8(eb + i * 32), sa);
          if (lane < 16) *(v4f*)&sm.a.sbuf[w][lane][0] = sa;
        }
        __syncthreads();
        if (tid < 32) {
          const int s = tid, sbb = s >> 4, sl = s & 15;
          float sc0 = 0.f, sc1 = 0.f, sc2 = 0.f;
#pragma unroll
          for (int k = 0; k < 4; ++k) {
            const float* sp = &sm.a.sbuf[sbb * 4 + k][sl][0];
            sc0 += sp[0]; sc1 += sp[1]; sc2 += sp[2];
          }
          float c0 = sc0, c1 = sc1, c2 = sc2;
#pragma unroll
          for (int m = 16; m >= 1; m >>= 1) {
            c0 = fmaxf(c0, __shfl_xor(c0, m));
            c1 = fmaxf(c1, __shfl_xor(c1, m));
            c2 = fmaxf(c2, __shfl_xor(c2, m));
          }
          float n0 = fmaxf(mml0, c0), n1 = fmaxf(mml1, c1), n2 = fmaxf(mml2, c2);
          float a0 = __expf(mml0 - n0), a1 = __expf(mml1 - n1), a2 = __expf(mml2 - n2);
          mml0 = n0; mml1 = n1; mml2 = n2;
          float w0 = __expf(sc0 - n0), w1 = __expf(sc1 - n1), w2 = __expf(sc2 - n2);
          sm.a.wl[s][0] = w0; sm.a.wl[s][1] = w1; sm.a.wl[s][2] = w2;
          float t0 = w0, t1 = w1, t2 = w2;
#pragma unroll
          for (int m = 16; m >= 1; m >>= 1) {
            t0 += __shfl_xor(t0, m); t1 += __shfl_xor(t1, m); t2 += __shfl_xor(t2, m);
          }
          lll0 = lll0 * a0 + t0; lll1 = lll1 * a1 + t1; lll2 = lll2 * a2 + t2;
          if (s == 0) {
            sm.a.alpha[0] = a0; sm.a.alpha[1] = a1; sm.a.alpha[2] = a2;
            sm.a.lfin[0] = lll0; sm.a.lfin[1] = lll1; sm.a.lfin[2] = lll2;
          }
        }
        __syncthreads();
        {
          const float a0 = sm.a.alpha[0], a1 = sm.a.alpha[1], a2 = sm.a.alpha[2];
          pv[0][0] *= a0; pv[0][1] *= a0;
          pv[1][0] *= a1; pv[1][1] *= a1;
          pv[2][0] *= a2; pv[2][1] *= a2;
#pragma unroll 4
          for (int s = 0; s < 32; ++s) {
            const float w0 = sm.a.wl[s][0], w1 = sm.a.wl[s][1], w2 = sm.a.wl[s][2];
            u32 ee = *(const u32*)&sm.a.e[s][d0];
            float e0 = bf2f((u16)ee), e1 = bf2f((u16)(ee >> 16));
            pv[0][0] += w0 * e0; pv[0][1] += w0 * e1;
            pv[1][0] += w1 * e0; pv[1][1] += w1 * e1;
            pv[2][0] += w2 * e0; pv[2][1] += w2 * e1;
          }
        }
        __syncthreads();
        if (c < 7) {
#pragma unroll
          for (int i = 0; i < 8; ++i)
            *(uint4*)&sm.a.e[sr][sc + i * 128] = pf[i];
        }
        __syncthreads();
      }
      {
        const float il0 = 1.0f / sm.a.lfin[0], il1 = 1.0f / sm.a.lfin[1],
                    il2 = 1.0f / sm.a.lfin[2];
        stg32(A.ad1 + (size_t)b * 2112 + d0,
              (u32)f2bf(pv[0][0] * il0) | ((u32)f2bf(pv[0][1] * il0) << 16));
        stg32(A.ad2 + (size_t)b * 3072 + d0,
              (u32)f2bf(pv[1][0] * il1) | ((u32)f2bf(pv[1][1] * il1) << 16));
        stg32(A.ad3 + (size_t)b * 3072 + d0,
              (u32)f2bf(pv[2][0] * il2) | ((u32)f2bf(pv[2][1] * il2) << 16));
      }
    } else {
      // WGs 128..255: copy h_old segments into cell A-staging (coherent)
      const int b = wg - 128;
      const u16* h1 = A.hd + (size_t)((0 * 2 + p) * 128 + b) * 1024;
      const u16* h2 = A.hd + (size_t)((1 * 2 + p) * 128 + b) * 1024;
      const u16* h3 = A.hd + (size_t)((2 * 2 + p) * 128 + b) * 1024;
      if (tid < 256) {
        stg64(A.ad1 + (size_t)b * 2112 + 1088 + tid * 4, ldg64(h1 + tid * 4));
      } else if (tid < 512) {
        int c4 = tid - 256;
        stg64(A.ad2 + (size_t)b * 3072 + 2048 + c4 * 4, ldg64(h2 + c4 * 4));
      }
      // h3 segment: reuse first 256 threads after a tiny offset loop
      if (tid < 256)
        stg64(A.ad3 + (size_t)b * 3072 + 2048 + tid * 4, ldg64(h3 + tid * 4));
    }
    gbar(A.flags, 256, wg, bt++);

    // ---------- cells 1..3: GEMM (B-frags from global, fragment-packed) + pointwise ----------
#pragma unroll
    for (int ci = 0; ci < 3; ++ci) {
      const int Kc = (ci == 0) ? 2112 : 3072;
      const u16* wb = (ci == 0 ? A.wd1 : ci == 1 ? A.wd2 : A.wd3) +
                      (size_t)wg * (size_t)(Kc >> 5) * 512;
      const u16* Ac = (ci == 0 ? A.ad1 : ci == 1 ? A.ad2 : A.ad3);
      {
        const u16* Ab = Ac + (size_t)(w * 16 + l15) * Kc + qd * 8;
        v4f a0 = (v4f){0.f, 0.f, 0.f, 0.f}, a1 = a0;
        const int NKB = Kc >> 5;
#pragma unroll 4
        for (int kkb = 0; kkb < NKB; kkb += 2) {
          a0 = mfma16(ld8c(Ab + kkb * 32), ld8(wb + kkb * 512 + lane * 8), a0);
          a1 = mfma16(ld8c(Ab + kkb * 32 + 32), ld8(wb + (kkb + 1) * 512 + lane * 8), a1);
        }
#pragma unroll
        for (int r = 0; r < 4; ++r)
          sm.c.glds[w * 16 + qd * 4 + r][l15] = a0[r] + a1[r];
      }
      __syncthreads();
      if (tid < 256) {
        float hv2[2];
#pragma unroll
        for (int jj = 0; jj < 2; ++jj) {
          const int jl = cjp * 2 + jj;
          float gi = sm.c.glds[cm_][0 * 4 + jl] + cbias[ci][0][jj];
          float gf = sm.c.glds[cm_][1 * 4 + jl] + cbias[ci][1][jj];
          float gg = sm.c.glds[cm_][2 * 4 + jl] + cbias[ci][2][jj];
          float go = sm.c.glds[cm_][3 * 4 + jl] + cbias[ci][3][jj];
          float cv = sigm(gf) * cstate[ci][jj] + sigm(gi) * tanhf(gg);
          cstate[ci][jj] = cv;
          hv2[jj] = sigm(go) * tanhf(cv);
        }
        u32 hv = (u32)f2bf(hv2[0]) | ((u32)f2bf(hv2[1]) << 16);
        const int jg = wg * 4 + cjp * 2;
        stg32(A.hd + (size_t)((ci * 2 + (p ^ 1)) * 128 + cm_) * 1024 + jg, hv);
        if (ci == 0) stg32(A.ad2 + (size_t)cm_ * 3072 + 1024 + jg, hv);
        else if (ci == 1) stg32(A.ad3 + (size_t)cm_ * 3072 + 1024 + jg, hv);
      }
      gbar(A.flags, 256, wg, bt++);
    }
  }
}

// ---------------- host ----------------
extern "C" void kernel_launch(void* const* d_in, const int* in_sizes, int n_in,
                              void* d_out, int out_size, void* d_ws, size_t ws_size,
                              hipStream_t stream) {
  char* ws = (char*)d_ws;
  size_t off = 0;
  auto alc = [&](size_t bytes) -> char* {
    char* pp = ws + off;
    off += (bytes + 255) & ~(size_t)255;
    return pp;
  };
  u16* XB = (u16*)alc(2097152ull * 2);
  u16* WF0 = (u16*)alc(2359296ull * 2);
  float* BF0 = (float*)alc(4096ull * 4);
  u16* WF1 = (u16*)alc(6291456ull * 2);
  float* BF1 = (float*)alc(4096ull * 4);
  u16* H0 = (u16*)alc(33554432ull * 2);
  u16* EO = (u16*)alc(33554432ull * 2);
  u16* HS0 = (u16*)alc(262144ull * 2);
  u16* HS1 = (u16*)alc(262144ull * 2);
  u16* XG = (u16*)alc(4194304ull * 2);   // [dir][8][nt 128][m 128][16] chunk buffer (8.4MB)
  u16* WQ = (u16*)alc(3145728ull * 2);
  u16* WOUT = (u16*)alc(65536ull * 2);
  u16* WD1 = (u16*)alc(8650752ull * 2);
  float* BD1 = (float*)alc(4096ull * 4);
  u16* WD2 = (u16*)alc(12582912ull * 2);
  float* BD2 = (float*)alc(4096ull * 4);
  u16* WD3 = (u16*)alc(12582912ull * 2);
  float* BD3 = (float*)alc(4096ull * 4);
  u16* QP = (u16*)alc(2097152ull * 2);
  u16* HD = (u16*)alc(786432ull * 2);
  u16* AD1 = (u16*)alc(270336ull * 2);
  u16* AD2 = (u16*)alc(393216ull * 2);
  u16* AD3 = (u16*)alc(393216ull * 2);
  u32* FLAGS = (u32*)alc(1536ull * 4);

  // zero state buffers (ws is poisoned before every call)
  k_zero<<<2, 256, 0, stream>>>((uint4*)FLAGS, 384);
  k_zero<<<1024, 256, 0, stream>>>((uint4*)QP, 262144);
  k_zero<<<128, 256, 0, stream>>>((uint4*)HS0, 32768);
  k_zero<<<128, 256, 0, stream>>>((uint4*)HS1, 32768);
  k_zero<<<384, 256, 0, stream>>>((uint4*)HD, 98304);

  // pack weights / inputs to bf16
  k_cvt<<<2048, 256, 0, stream>>>((const float*)d_in[0], XB, 2097152);
  k_cvt<<<64, 256, 0, stream>>>((const float*)d_in[22], WOUT, 65536);
  k_pack_enc<<<4096, 256, 0, stream>>>((const float*)d_in[1], (const float*)d_in[2],
                                       (const float*)d_in[3], WF0, BF0, 64);
  k_pack_enc<<<4096, 256, 0, stream>>>((const float*)d_in[4], (const float*)d_in[5],
                                       (const float*)d_in[6], WF1, BF1, 1024);
  k_pack_attnT<<<3072, 256, 0, stream>>>((const float*)d_in[7], (const float*)d_in[9],
                                         (const float*)d_in[11], WQ);
  k_pack_decf<<<4096, 256, 0, stream>>>((const float*)d_in[13], (const float*)d_in[14],
                                        (const float*)d_in[15], WD1, BD1, 1088);
  k_pack_decf<<<4096, 256, 0, stream>>>((const float*)d_in[16], (const float*)d_in[17],
                                        (const float*)d_in[18], WD2, BD2, 2048);
  k_pack_decf<<<4096, 256, 0, stream>>>((const float*)d_in[19], (const float*)d_in[20],
                                        (const float*)d_in[21], WD3, BD3, 2048);

  // encoder layers (persistent, 256 WGs x 512 threads each)
  k_rec<<<256, 512, 0, stream>>>(XB, 64, WF0, BF0, XG, HS0, H0, FLAGS);
  k_rec<<<256, 512, 0, stream>>>(H0, 1024, WF1, BF1, XG, HS1, EO, FLAGS + 256);

  // decoder (persistent, 256 WGs x 512 threads)
  DecArgs da;
  da.x = (const float*)d_in[0];
  da.outb = (const float*)d_in[23];
  da.dout = (float*)d_out;
  da.eo = EO; da.wq = WQ; da.wout = WOUT;
  da.wd1 = WD1; da.wd2 = WD2; da.wd3 = WD3;
  da.bd1 = BD1; da.bd2 = BD2; da.bd3 = BD3;
  da.qp = QP; da.hd = HD; da.ad1 = AD1; da.ad2 = AD2; da.ad3 = AD3;
  da.flags = FLAGS + 512;
  k_dec<<<256, 512, 0, stream>>>(da);
}